// Round 15
// baseline (100.388 us; speedup 1.0000x reference)
//
#include <hip/hip_runtime.h>
#include <string.h>

#define NQ 14
#define NSTATE (1 << NQ)       // 16384 amplitudes
#define NL 3
#define MAXP 12
#define BT 1024                // fallback kernel block
#define NWAVES (BT / 64)
#define NEX 11                 // extra-gate combo menu size
#define BTS 512                // split kernels block
#define NWS (BTS / 64)
#define HSTATE 8192            // half state (split)

// ============================================================
// Split design (v2): entries {0,1,2} in kernel1, {3,4,5} in kernel2.
// Per chunk a functional phi with phi(chunk masks)=0 exists (span rank
// <= 12 < 14): each element's state splits into two non-interacting 8K
// halves per chunk. 2 blocks/element * 128 = 256 blocks -> all CUs busy.
// The inter-kernel exchange is BF16-PACKED (8 MB total, RNE) with a
// GF(2)-chosen slot layout so both sides are fully coalesced; logit
// error from bf16 ~1e-4 << 1.44e-2 threshold. Params live at d_ws+8MB.
// Fallback = verified round-10 kernel, TEMPLATED BY FAILURE REASON so
// the profile's Kernel_Name reveals why the split didn't run:
//   qsim_fb<1>=pack shape, <2>=GF construction, <3>=T search, <4>=ws.
// ============================================================

// ---------------- shared device helpers ----------------
struct C2x2 { float2 m[2][2]; };

__device__ __forceinline__ float2 cmul(float2 a, float2 b) {
    return make_float2(a.x * b.x - a.y * b.y, a.x * b.y + a.y * b.x);
}
__device__ __forceinline__ float2 cmac(float2 acc, float2 a, float2 b) {
    acc.x = fmaf(a.x, b.x, fmaf(-a.y, b.y, acc.x));
    acc.y = fmaf(a.x, b.y, fmaf(a.y, b.x, acc.y));
    return acc;
}
// PennyLane Rot(phi,theta,omega) = RZ(omega) RY(theta) RZ(phi)
__device__ __forceinline__ C2x2 rot_gate(const float* qp) {
    float phi = qp[0], th = qp[1], om = qp[2];
    float ct, stt; __sincosf(0.5f * th, &stt, &ct);
    float sa, ca; __sincosf(0.5f * (phi + om), &sa, &ca);
    float sb, cb; __sincosf(0.5f * (phi - om), &sb, &cb);
    C2x2 G;
    G.m[0][0] = make_float2(ca * ct, -sa * ct);
    G.m[0][1] = make_float2(-cb * stt, -sb * stt);
    G.m[1][0] = make_float2(cb * stt, -sb * stt);
    G.m[1][1] = make_float2(ca * ct, sa * ct);
    return G;
}
// G := G * RX(ang)
__device__ __forceinline__ C2x2 fuse_rx(C2x2 G, float ang) {
    float sh, ch; __sincosf(0.5f * ang, &sh, &ch);
    float2 c = make_float2(ch, 0.f), is = make_float2(0.f, -sh);
    C2x2 R;
    #pragma unroll
    for (int i = 0; i < 2; ++i) {
        R.m[i][0] = cmac(cmul(G.m[i][0], c), G.m[i][1], is);
        R.m[i][1] = cmac(cmul(G.m[i][1], c), G.m[i][0], is);
    }
    return R;
}

// bf16 pair pack/unpack (RNE)
__device__ __forceinline__ unsigned pk_bf(float2 v) {
    unsigned bx = __float_as_uint(v.x), by = __float_as_uint(v.y);
    bx = (bx + 0x7FFFu + ((bx >> 16) & 1u)) >> 16;
    by = (by + 0x7FFFu + ((by >> 16) & 1u)) >> 16;
    return (bx & 0xFFFFu) | (by << 16);
}
__device__ __forceinline__ float2 upk_bf(unsigned u) {
    return make_float2(__uint_as_float((u & 0xFFFFu) << 16),
                       __uint_as_float(u & 0xFFFF0000u));
}

// basis gates: unit combos, orientation = logical bit q; params from LDS psh
#define APPLY_BASIS(PS)                                                     \
    {                                                                       \
        _Pragma("unroll")                                                   \
        for (int q = 0; q < 4; ++q) {                                       \
            if (q < (int)nwr) {                                             \
                const int gi = (int)psh.pass[PS].gidx[q] * 4;               \
                float2 g00 = gbuf[gi + 0], g01 = gbuf[gi + 1];              \
                float2 g10 = gbuf[gi + 2], g11 = gbuf[gi + 3];              \
                _Pragma("unroll")                                           \
                for (int i = 0; i < 16; ++i) {                              \
                    if (!((i >> q) & 1)) {                                  \
                        const int i1 = i | (1 << q);                        \
                        float2 a0 = a[i], a1 = a[i1];                       \
                        float2 n0 = cmac(cmul(g00, a0), g01, a1);           \
                        float2 n1 = cmac(cmul(g10, a0), g11, a1);           \
                        a[i] = n0; a[i1] = n1;                              \
                    }                                                       \
                }                                                           \
            }                                                               \
        }                                                                   \
    }

// ---------------- fallback kernel (verbatim round-10, reason-templated) ----
struct PassG {
    unsigned cmb8[16];
    unsigned R[10];
    unsigned gidx[4];
    unsigned nw;
    unsigned epm;
    unsigned eg[11];     // sga(14b) | gidx<<16
    unsigned parw[11];
    unsigned pad[2];
};
struct ParamsG {
    PassG pass[MAXP];
    unsigned ms[NQ];
    unsigned fmask[NQ];
    unsigned initIW[10];
};
#define PG_WORDS ((int)(sizeof(ParamsG) / 4))

template<int C>
__device__ __forceinline__ void apply_extra(float2 a[16], const float2* gb,
        unsigned w1, unsigned pw, unsigned rep)
{
    const unsigned sga = w1 & 0x3FFFu;
    const int gi = (int)(w1 >> 16) * 4;
    const unsigned og = __popc(rep & sga) & 1u;
    const unsigned swv = pw ^ (og ? 0xFFFFu : 0u);
    float2 g00 = gb[gi + 0], g01 = gb[gi + 1], g10 = gb[gi + 2], g11 = gb[gi + 3];
    const int LB = C & (-C);
    #pragma unroll
    for (int i = 0; i < 16; ++i) {
        if (!(i & LB)) {
            const int i1 = i ^ C;
            const bool sw = (swv >> i) & 1u;
            float2 x0 = sw ? a[i1] : a[i];
            float2 x1 = sw ? a[i]  : a[i1];
            float2 n0 = cmac(cmul(g00, x0), g01, x1);
            float2 n1 = cmac(cmul(g10, x0), g11, x1);
            a[i]  = sw ? n1 : n0;
            a[i1] = sw ? n0 : n1;
        }
    }
}

#define APPLY_EXTRAS(PS)                                                    \
    {                                                                       \
        if (epm) {                                                          \
            if (epm & (1u<<0))  apply_extra<3> (a, gbuf, psh.pass[PS].eg[0],  psh.pass[PS].parw[0],  rn); \
            if (epm & (1u<<1))  apply_extra<5> (a, gbuf, psh.pass[PS].eg[1],  psh.pass[PS].parw[1],  rn); \
            if (epm & (1u<<2))  apply_extra<6> (a, gbuf, psh.pass[PS].eg[2],  psh.pass[PS].parw[2],  rn); \
            if (epm & (1u<<3))  apply_extra<9> (a, gbuf, psh.pass[PS].eg[3],  psh.pass[PS].parw[3],  rn); \
            if (epm & (1u<<4))  apply_extra<10>(a, gbuf, psh.pass[PS].eg[4],  psh.pass[PS].parw[4],  rn); \
            if (epm & (1u<<5))  apply_extra<12>(a, gbuf, psh.pass[PS].eg[5],  psh.pass[PS].parw[5],  rn); \
            if (epm & (1u<<6))  apply_extra<7> (a, gbuf, psh.pass[PS].eg[6],  psh.pass[PS].parw[6],  rn); \
            if (epm & (1u<<7))  apply_extra<11>(a, gbuf, psh.pass[PS].eg[7],  psh.pass[PS].parw[7],  rn); \
            if (epm & (1u<<8))  apply_extra<13>(a, gbuf, psh.pass[PS].eg[8],  psh.pass[PS].parw[8],  rn); \
            if (epm & (1u<<9))  apply_extra<14>(a, gbuf, psh.pass[PS].eg[9],  psh.pass[PS].parw[9],  rn); \
            if (epm & (1u<<10)) apply_extra<15>(a, gbuf, psh.pass[PS].eg[10], psh.pass[PS].parw[10], rn); \
        }                                                                   \
    }

template<int REASON>
__global__ __launch_bounds__(BT, 4) void qsim_fb(
    const float* __restrict__ x, const float* __restrict__ qw,
    const float* __restrict__ wl, const float* __restrict__ bl,
    float* __restrict__ out, const ParamsG* __restrict__ pp, int np)
{
    __shared__ float2 st[NSTATE];
    __shared__ float2 gbuf[NL * NQ * 4];
    __shared__ float2 ubuf[NQ][2];
    __shared__ float red[NWAVES];
    __shared__ __align__(16) ParamsG psh;

    const int tid = threadIdx.x;
    const int b = blockIdx.x;

    {
        const unsigned* srcw = (const unsigned*)pp;
        unsigned* dstw = (unsigned*)&psh;
        for (int i = tid; i < PG_WORDS; i += BT) dstw[i] = srcw[i];
    }
    if (tid < NL * NQ) {
        int l = tid / NQ, w = tid % NQ;
        C2x2 G = rot_gate(qw + tid * 3);
        if (l == 0) {
            G = fuse_rx(G, x[b * NQ + w]);
            ubuf[w][0] = G.m[0][0];
            ubuf[w][1] = G.m[1][0];
        }
        gbuf[tid * 4 + 0] = G.m[0][0];
        gbuf[tid * 4 + 1] = G.m[0][1];
        gbuf[tid * 4 + 2] = G.m[1][0];
        gbuf[tid * 4 + 3] = G.m[1][1];
    }

    char* sb = (char*)st;
    float2 a[16];
    unsigned addr[16];
    unsigned rn;

    __syncthreads();

    {
        unsigned r0 = 0, b0 = 0;
        #pragma unroll
        for (int j = 0; j < 10; ++j) {
            const unsigned sel = (tid >> j) & 1;
            r0 ^= sel ? psh.pass[0].R[j] : 0u;
            b0 ^= sel ? psh.initIW[j] : 0u;
        }
        rn = r0;
        const unsigned rb = rn << 3;
        float2 c = ubuf[0][b0 & 1];
        #pragma unroll
        for (int w = 1; w < 10; ++w)
            c = cmul(c, ubuf[w][(b0 >> w) & 1]);
        a[0] = cmul(c, ubuf[10][0]);
        a[1] = cmul(c, ubuf[10][1]);
        #pragma unroll
        for (int i = 0; i < 2; ++i) {
            a[2 + i] = cmul(a[i], ubuf[11][1]);
            a[i]     = cmul(a[i], ubuf[11][0]);
        }
        #pragma unroll
        for (int i = 0; i < 4; ++i) {
            a[4 + i] = cmul(a[i], ubuf[12][1]);
            a[i]     = cmul(a[i], ubuf[12][0]);
        }
        #pragma unroll
        for (int i = 0; i < 8; ++i) {
            a[8 + i] = cmul(a[i], ubuf[13][1]);
            a[i]     = cmul(a[i], ubuf[13][0]);
        }
        #pragma unroll
        for (int i = 0; i < 16; ++i)
            *(float2*)(sb + (rb ^ psh.pass[0].cmb8[i])) = a[i];
    }

    {
        unsigned rt = 0;
        #pragma unroll
        for (int j = 0; j < 10; ++j)
            rt ^= ((tid >> j) & 1) ? psh.pass[1].R[j] : 0u;
        rn = rt;
    }

    #pragma unroll 1
    for (int ps = 1; ps < np - 1; ++ps) {
        __syncthreads();
        const unsigned rb = rn << 3;
        #pragma unroll
        for (int i = 0; i < 16; ++i) addr[i] = rb ^ psh.pass[ps].cmb8[i];
        #pragma unroll
        for (int i = 0; i < 16; ++i)
            a[i] = *(const float2*)(sb + addr[i]);
        unsigned rt = 0;
        #pragma unroll
        for (int j = 0; j < 10; ++j)
            rt ^= ((tid >> j) & 1) ? psh.pass[ps + 1].R[j] : 0u;
        const unsigned nwr = psh.pass[ps].nw;
        APPLY_BASIS(ps);
        const unsigned epm = psh.pass[ps].epm;
        APPLY_EXTRAS(ps);
        #pragma unroll
        for (int i = 0; i < 16; ++i)
            *(float2*)(sb + addr[i]) = a[i];
        rn = rt;
    }

    float acc = 0.f;
    {
        const int ps = np - 1;
        __syncthreads();
        const unsigned rb = rn << 3;
        #pragma unroll
        for (int i = 0; i < 16; ++i) addr[i] = rb ^ psh.pass[ps].cmb8[i];
        #pragma unroll
        for (int i = 0; i < 16; ++i)
            a[i] = *(const float2*)(sb + addr[i]);
        const unsigned nwr = psh.pass[ps].nw;
        APPLY_BASIS(ps);
        const unsigned epm = psh.pass[ps].epm;
        APPLY_EXTRAS(ps);

        float A[16];
        #pragma unroll
        for (int i = 0; i < 16; ++i) A[i] = 0.f;
        #pragma unroll
        for (int w = 0; w < NQ; ++w) {
            float v = wl[w];
            unsigned p0 = __popc(rn & psh.ms[w]) & 1u;
            float vs = p0 ? -v : v;
            const unsigned fm = psh.fmask[w];
            #pragma unroll
            for (int i = 0; i < 16; ++i)
                A[i] += ((fm >> i) & 1u) ? -vs : vs;
        }
        #pragma unroll
        for (int i = 0; i < 16; ++i)
            acc = fmaf(fmaf(a[i].x, a[i].x, a[i].y * a[i].y), A[i], acc);
    }

    #pragma unroll
    for (int off = 32; off > 0; off >>= 1) acc += __shfl_down(acc, off, 64);
    if ((tid & 63) == 0) red[tid >> 6] = acc;
    __syncthreads();
    if (tid == 0) {
        float s2 = 0.f;
        #pragma unroll
        for (int i = 0; i < NWAVES; ++i) s2 += red[i];
        out[b] = s2 + bl[0];
    }
}

// ---------------- SPLIT kernels ----------------
struct PassK {
    unsigned cmb8[16];   // T-image of combos, <<3
    unsigned R[9];       // T-image of complement (bank pivots first)
    unsigned Ug;         // T-image of the g-direction
    unsigned gidx[4];
    unsigned nw, epm;
    unsigned eg[NEX];    // sga13 | sgc<<13 | gidx<<16
    unsigned parw[NEX];
};
struct ParamsK1 {
    PassK pass[3];       // entry 0 = init
    unsigned initIW[9];  // wire-bit words of raw Rv (reordered with R)
    unsigned initIWg;    // wire-bit word of raw Ug
    unsigned SK[12];     // slot-bit -> LDS byte-offset images
    unsigned SKj, SKg;
    unsigned pad;
};
struct ParamsK2 {
    PassK pass[3];
    unsigned SL[13], SLj;
    unsigned ms[NQ];     // ms13 | msg<<13
    unsigned fmask[NQ];
};
struct ParamsS { ParamsK1 k1; ParamsK2 k2; };

template<int C>
__device__ __forceinline__ void apply_extra_s(float2 a[16], const float2* gb,
        unsigned w1, unsigned pw, unsigned rep, unsigned gbit)
{
    const int gi = (int)(w1 >> 16) * 4;
    const unsigned og = ((unsigned)__popc(rep & (w1 & 0x1FFFu)) ^ ((w1 >> 13) & gbit)) & 1u;
    const unsigned swv = pw ^ (og ? 0xFFFFu : 0u);
    float2 g00 = gb[gi + 0], g01 = gb[gi + 1], g10 = gb[gi + 2], g11 = gb[gi + 3];
    const int LB = C & (-C);
    #pragma unroll
    for (int i = 0; i < 16; ++i) {
        if (!(i & LB)) {
            const int i1 = i ^ C;
            const bool sw = (swv >> i) & 1u;
            float2 x0 = sw ? a[i1] : a[i];
            float2 x1 = sw ? a[i]  : a[i1];
            float2 n0 = cmac(cmul(g00, x0), g01, x1);
            float2 n1 = cmac(cmul(g10, x0), g11, x1);
            a[i]  = sw ? n1 : n0;
            a[i1] = sw ? n0 : n1;
        }
    }
}

#define APPLY_EXTRAS_S(PS, GB)                                              \
    {                                                                       \
        if (epm) {                                                          \
            if (epm & (1u<<0))  apply_extra_s<3> (a, gbuf, psh.pass[PS].eg[0],  psh.pass[PS].parw[0],  rn, GB); \
            if (epm & (1u<<1))  apply_extra_s<5> (a, gbuf, psh.pass[PS].eg[1],  psh.pass[PS].parw[1],  rn, GB); \
            if (epm & (1u<<2))  apply_extra_s<6> (a, gbuf, psh.pass[PS].eg[2],  psh.pass[PS].parw[2],  rn, GB); \
            if (epm & (1u<<3))  apply_extra_s<9> (a, gbuf, psh.pass[PS].eg[3],  psh.pass[PS].parw[3],  rn, GB); \
            if (epm & (1u<<4))  apply_extra_s<10>(a, gbuf, psh.pass[PS].eg[4],  psh.pass[PS].parw[4],  rn, GB); \
            if (epm & (1u<<5))  apply_extra_s<12>(a, gbuf, psh.pass[PS].eg[5],  psh.pass[PS].parw[5],  rn, GB); \
            if (epm & (1u<<6))  apply_extra_s<7> (a, gbuf, psh.pass[PS].eg[6],  psh.pass[PS].parw[6],  rn, GB); \
            if (epm & (1u<<7))  apply_extra_s<11>(a, gbuf, psh.pass[PS].eg[7],  psh.pass[PS].parw[7],  rn, GB); \
            if (epm & (1u<<8))  apply_extra_s<13>(a, gbuf, psh.pass[PS].eg[8],  psh.pass[PS].parw[8],  rn, GB); \
            if (epm & (1u<<9))  apply_extra_s<14>(a, gbuf, psh.pass[PS].eg[9],  psh.pass[PS].parw[9],  rn, GB); \
            if (epm & (1u<<10)) apply_extra_s<15>(a, gbuf, psh.pass[PS].eg[10], psh.pass[PS].parw[10], rn, GB); \
        }                                                                   \
    }

__global__ __launch_bounds__(BTS, 4) void qsim_k1(
    const float* __restrict__ x, const float* __restrict__ qw,
    const ParamsS* __restrict__ pp, unsigned* __restrict__ stbuf,
    float* __restrict__ out)
{
    __shared__ float2 st[HSTATE];
    __shared__ float2 gbuf[NL * NQ * 4];
    __shared__ float2 ubuf[NQ][2];
    __shared__ ParamsK1 psh;

    const int tid = threadIdx.x;
    const int e = blockIdx.x >> 1, g1 = blockIdx.x & 1;

    {
        const unsigned* s = (const unsigned*)&pp->k1;
        unsigned* d = (unsigned*)&psh;
        for (int i = tid; i < (int)(sizeof(ParamsK1) / 4); i += BTS) d[i] = s[i];
    }
    if (tid < NL * NQ) {
        int l = tid / NQ, w = tid % NQ;
        C2x2 G = rot_gate(qw + tid * 3);
        if (l == 0) {
            G = fuse_rx(G, x[e * NQ + w]);
            ubuf[w][0] = G.m[0][0];
            ubuf[w][1] = G.m[1][0];
        }
        gbuf[tid * 4 + 0] = G.m[0][0];
        gbuf[tid * 4 + 1] = G.m[0][1];
        gbuf[tid * 4 + 2] = G.m[1][0];
        gbuf[tid * 4 + 3] = G.m[1][1];
    }
    char* sb = (char*)st;
    __syncthreads();

    // entry 0: analytic product-state init of this half
    {
        unsigned rn = g1 ? psh.pass[0].Ug : 0u;
        unsigned b0 = g1 ? psh.initIWg : 0u;
        #pragma unroll
        for (int j5 = 0; j5 < 9; ++j5) {
            const unsigned sel = (tid >> j5) & 1u;
            rn ^= sel ? psh.pass[0].R[j5] : 0u;
            b0 ^= sel ? psh.initIW[j5] : 0u;
        }
        const unsigned rb = rn << 3;
        float2 a[16];
        float2 c = ubuf[0][b0 & 1];
        #pragma unroll
        for (int w = 1; w < 10; ++w)
            c = cmul(c, ubuf[w][(b0 >> w) & 1]);
        a[0] = cmul(c, ubuf[10][0]);
        a[1] = cmul(c, ubuf[10][1]);
        #pragma unroll
        for (int i = 0; i < 2; ++i) {
            a[2 + i] = cmul(a[i], ubuf[11][1]);
            a[i]     = cmul(a[i], ubuf[11][0]);
        }
        #pragma unroll
        for (int i = 0; i < 4; ++i) {
            a[4 + i] = cmul(a[i], ubuf[12][1]);
            a[i]     = cmul(a[i], ubuf[12][0]);
        }
        #pragma unroll
        for (int i = 0; i < 8; ++i) {
            a[8 + i] = cmul(a[i], ubuf[13][1]);
            a[i]     = cmul(a[i], ubuf[13][0]);
        }
        #pragma unroll
        for (int i = 0; i < 16; ++i)
            *(float2*)(sb + (rb ^ psh.pass[0].cmb8[i])) = a[i];
    }

    // entries 1,2
    for (int p5 = 1; p5 < 3; ++p5) {
        __syncthreads();
        unsigned rn = g1 ? psh.pass[p5].Ug : 0u;
        #pragma unroll
        for (int j5 = 0; j5 < 9; ++j5)
            rn ^= ((tid >> j5) & 1u) ? psh.pass[p5].R[j5] : 0u;
        const unsigned rb = rn << 3;
        unsigned addr[16];
        #pragma unroll
        for (int i = 0; i < 16; ++i) addr[i] = rb ^ psh.pass[p5].cmb8[i];
        float2 a[16];
        #pragma unroll
        for (int i = 0; i < 16; ++i) a[i] = *(const float2*)(sb + addr[i]);
        const unsigned nwr = psh.pass[p5].nw;
        APPLY_BASIS(p5);
        const unsigned epm = psh.pass[p5].epm;
        APPLY_EXTRAS_S(p5, (unsigned)g1);
        #pragma unroll
        for (int i = 0; i < 16; ++i) *(float2*)(sb + addr[i]) = a[i];
    }
    __syncthreads();

    // gather -> global, bf16-packed (coalesced: slot = i<<9 | tid per chunk)
    {
        unsigned tb = g1 ? psh.SKg : 0u;
        #pragma unroll
        for (int k = 0; k < 9; ++k)
            tb ^= ((tid >> k) & 1u) ? psh.SK[k] : 0u;
        #pragma unroll
        for (int j2 = 0; j2 < 2; ++j2) {
            const unsigned bb = tb ^ (j2 ? psh.SKj : 0u);
            unsigned* gdst = stbuf + ((((size_t)e * 2 + j2) * 2 + g1) << 12) + tid;
            #pragma unroll
            for (int i = 0; i < 8; ++i) {
                unsigned la = bb;
                if (i & 1) la ^= psh.SK[9];
                if (i & 2) la ^= psh.SK[10];
                if (i & 4) la ^= psh.SK[11];
                gdst[i * 512] = pk_bf(*(const float2*)(sb + la));
            }
        }
        if (g1 == 0 && tid == 0) out[e] = 0.f;  // replay-safe zero before k2 atomics
    }
}

__global__ __launch_bounds__(BTS, 4) void qsim_k2(
    const float* __restrict__ x, const float* __restrict__ qw,
    const float* __restrict__ wl, const float* __restrict__ bl,
    const ParamsS* __restrict__ pp, const unsigned* __restrict__ stbuf,
    float* __restrict__ out)
{
    __shared__ float2 st[HSTATE];
    __shared__ float2 gbuf[NL * NQ * 4];
    __shared__ float2 ubuf[NQ][2];
    __shared__ ParamsK2 psh;
    __shared__ float red[NWS];

    const int tid = threadIdx.x;
    const int e = blockIdx.x >> 1, j = blockIdx.x & 1;

    {
        const unsigned* s = (const unsigned*)&pp->k2;
        unsigned* d = (unsigned*)&psh;
        for (int i = tid; i < (int)(sizeof(ParamsK2) / 4); i += BTS) d[i] = s[i];
    }
    if (tid < NL * NQ) {
        int l = tid / NQ, w = tid % NQ;
        C2x2 G = rot_gate(qw + tid * 3);
        if (l == 0) {
            G = fuse_rx(G, x[e * NQ + w]);
            ubuf[w][0] = G.m[0][0];
            ubuf[w][1] = G.m[1][0];
        }
        gbuf[tid * 4 + 0] = G.m[0][0];
        gbuf[tid * 4 + 1] = G.m[0][1];
        gbuf[tid * 4 + 2] = G.m[1][0];
        gbuf[tid * 4 + 3] = G.m[1][1];
    }
    char* sb = (char*)st;
    __syncthreads();

    // scatter in from global, bf16-unpacked (coalesced: slot = i<<9 | tid)
    {
        unsigned tb = j ? psh.SLj : 0u;
        #pragma unroll
        for (int k = 0; k < 9; ++k)
            tb ^= ((tid >> k) & 1u) ? psh.SL[k] : 0u;
        const unsigned* gsrc = stbuf + (((size_t)e * 2 + j) << 13) + tid;
        #pragma unroll
        for (int i = 0; i < 16; ++i) {
            float2 v = upk_bf(gsrc[i * 512]);
            unsigned la = tb;
            if (i & 1) la ^= psh.SL[9];
            if (i & 2) la ^= psh.SL[10];
            if (i & 4) la ^= psh.SL[11];
            if (i & 8) la ^= psh.SL[12];
            *(float2*)(sb + la) = v;
        }
    }

    // entries 0,1 (global entries 3,4)
    for (int p5 = 0; p5 < 2; ++p5) {
        __syncthreads();
        unsigned rn = j ? psh.pass[p5].Ug : 0u;
        #pragma unroll
        for (int j5 = 0; j5 < 9; ++j5)
            rn ^= ((tid >> j5) & 1u) ? psh.pass[p5].R[j5] : 0u;
        const unsigned rb = rn << 3;
        unsigned addr[16];
        #pragma unroll
        for (int i = 0; i < 16; ++i) addr[i] = rb ^ psh.pass[p5].cmb8[i];
        float2 a[16];
        #pragma unroll
        for (int i = 0; i < 16; ++i) a[i] = *(const float2*)(sb + addr[i]);
        const unsigned nwr = psh.pass[p5].nw;
        APPLY_BASIS(p5);
        const unsigned epm = psh.pass[p5].epm;
        APPLY_EXTRAS_S(p5, (unsigned)j);
        #pragma unroll
        for (int i = 0; i < 16; ++i) *(float2*)(sb + addr[i]) = a[i];
    }

    // final entry + fused measurement
    float acc = 0.f;
    {
        __syncthreads();
        unsigned rn = j ? psh.pass[2].Ug : 0u;
        #pragma unroll
        for (int j5 = 0; j5 < 9; ++j5)
            rn ^= ((tid >> j5) & 1u) ? psh.pass[2].R[j5] : 0u;
        const unsigned rb = rn << 3;
        unsigned addr[16];
        #pragma unroll
        for (int i = 0; i < 16; ++i) addr[i] = rb ^ psh.pass[2].cmb8[i];
        float2 a[16];
        #pragma unroll
        for (int i = 0; i < 16; ++i) a[i] = *(const float2*)(sb + addr[i]);
        const unsigned nwr = psh.pass[2].nw;
        APPLY_BASIS(2);
        const unsigned epm = psh.pass[2].epm;
        APPLY_EXTRAS_S(2, (unsigned)j);

        float A[16];
        #pragma unroll
        for (int i = 0; i < 16; ++i) A[i] = 0.f;
        #pragma unroll
        for (int w = 0; w < NQ; ++w) {
            float v = wl[w];
            const unsigned msw = psh.ms[w];
            unsigned p0 = ((unsigned)__popc(rn & (msw & 0x1FFFu)) ^ ((msw >> 13) & (unsigned)j)) & 1u;
            float vs = p0 ? -v : v;
            const unsigned fm = psh.fmask[w];
            #pragma unroll
            for (int i = 0; i < 16; ++i)
                A[i] += ((fm >> i) & 1u) ? -vs : vs;
        }
        #pragma unroll
        for (int i = 0; i < 16; ++i)
            acc = fmaf(fmaf(a[i].x, a[i].x, a[i].y * a[i].y), A[i], acc);
    }

    #pragma unroll
    for (int off = 32; off > 0; off >>= 1) acc += __shfl_down(acc, off, 64);
    if ((tid & 63) == 0) red[tid >> 6] = acc;
    __syncthreads();
    if (tid == 0) {
        float s2 = 0.f;
        #pragma unroll
        for (int i = 0; i < NWS; ++i) s2 += red[i];
        atomicAdd(out + e, s2 + (j == 0 ? bl[0] : 0.f));
    }
}

// ---------------- host-side GF(2) helpers ----------------
struct GF2Basis {
    unsigned piv[NQ];
    GF2Basis() { for (int i = 0; i < NQ; ++i) piv[i] = 0; }
    bool insert(unsigned v) {
        for (int bb = NQ - 1; bb >= 0; --bb) {
            if (!((v >> bb) & 1)) continue;
            if (piv[bb]) v ^= piv[bb];
            else { piv[bb] = v; return true; }
        }
        return false;
    }
};

static inline int par16(unsigned v) { return __builtin_parity(v); }
static inline unsigned lcg_next(unsigned& s) { s = s * 1664525u + 1013904223u; return s >> 8; }

static unsigned gf_apply(const unsigned* C, unsigned v) {
    unsigned r = 0;
    while (v) { int j = __builtin_ctz(v); v &= v - 1; r ^= C[j]; }
    return r;
}

static bool gf_invert(const unsigned* C, unsigned* Ci) {
    unsigned rows[NQ], irows[NQ];
    for (int i = 0; i < NQ; ++i) {
        unsigned r = 0;
        for (int j = 0; j < NQ; ++j) r |= ((C[j] >> i) & 1u) << j;
        rows[i] = r; irows[i] = 1u << i;
    }
    for (int c = 0; c < NQ; ++c) {
        int p = -1;
        for (int r = c; r < NQ; ++r) if ((rows[r] >> c) & 1u) { p = r; break; }
        if (p < 0) return false;
        unsigned t = rows[p]; rows[p] = rows[c]; rows[c] = t;
        t = irows[p]; irows[p] = irows[c]; irows[c] = t;
        for (int r = 0; r < NQ; ++r)
            if (r != c && ((rows[r] >> c) & 1u)) { rows[r] ^= rows[c]; irows[r] ^= irows[c]; }
    }
    for (int j = 0; j < NQ; ++j) {
        unsigned col = 0;
        for (int i = 0; i < NQ; ++i) col |= ((irows[i] >> j) & 1u) << i;
        Ci[j] = col;
    }
    return true;
}

static void rows_to_cols(const unsigned* rows, unsigned* cols) {
    for (int j = 0; j < NQ; ++j) {
        unsigned c = 0;
        for (int i = 0; i < NQ; ++i) c |= ((rows[i] >> j) & 1u) << i;
        cols[j] = c;
    }
}

// functional f with par(f & b) = 0 for all b in bas[0..n); 0 if none found
static unsigned gf_nullfunc(const unsigned* bas, int n) {
    unsigned rows[NQ]; int nr = 0;
    for (int i = 0; i < n; ++i) {
        unsigned v = bas[i];
        for (int k = 0; k < nr; ++k) {
            int p = 31 - __builtin_clz(rows[k]);
            if ((v >> p) & 1u) v ^= rows[k];
        }
        if (v) rows[nr++] = v;
    }
    for (int k = 0; k < nr; ++k) {
        int p = 31 - __builtin_clz(rows[k]);
        for (int k2 = 0; k2 < nr; ++k2)
            if (k2 != k && ((rows[k2] >> p) & 1u)) rows[k2] ^= rows[k];
    }
    unsigned pivmask = 0;
    for (int k = 0; k < nr; ++k) pivmask |= 1u << (31 - __builtin_clz(rows[k]));
    for (int f = 0; f < NQ; ++f) {
        if ((pivmask >> f) & 1u) continue;
        unsigned xx = 1u << f;
        for (int k = 0; k < nr; ++k)
            if ((rows[k] >> f) & 1u) xx |= 1u << (31 - __builtin_clz(rows[k]));
        bool ok = true;
        for (int i = 0; i < n && ok; ++i) if (par16(bas[i] & xx)) ok = false;
        if (ok) return xx;
    }
    return 0;
}

static unsigned addr_img(const unsigned* T, unsigned v) {  // 13 functionals
    unsigned r = 0;
    for (int i = 0; i < 13; ++i) r |= (unsigned)(par16(T[i] & v) & 1) << i;
    return r;
}

// ---------------- shared circuit build + packer ----------------
struct RawEntry {
    unsigned mm[4], ss[4];
    unsigned char gidx[4], nw;
    int exgate[NEX];
    unsigned exsel[NEX], exT[NEX];
};
static const int EXC[NEX] = {3, 5, 6, 9, 10, 12, 7, 11, 13, 14, 15};

static int build_and_pack(RawEntry* raw, unsigned* msIdx) {
    int c2s[16]; for (int i = 0; i < 16; ++i) c2s[i] = -1;
    for (int k = 0; k < NEX; ++k) c2s[EXC[k]] = k;

    unsigned gs[NL * NQ], gm[NL * NQ];
    int ggi[NL * NQ];
    unsigned s[NQ], m[NQ];
    for (int w = 0; w < NQ; ++w) s[w] = m[w] = 1u << (NQ - 1 - w);
    int ng = 0;
    for (int l = 0; l < NL; ++l) {
        if (l > 0) {
            for (int w = 0; w < NQ; ++w) {
                gs[ng] = s[w]; gm[ng] = m[w]; ggi[ng] = l * NQ + w; ++ng;
            }
        }
        int r = (l % (NQ - 1)) + 1;
        for (int w = 0; w < NQ; ++w) {
            int c = w, t = (w + r) % NQ;
            s[t] ^= s[c];
            m[c] ^= m[t];
        }
    }
    for (int w = 0; w < NQ; ++w) msIdx[w] = s[w];

    for (int p = 0; p < MAXP; ++p)
        for (int k = 0; k < NEX; ++k) raw[p].exgate[k] = -1;

    // entry 0: init (group aligned to wires 10..13)
    for (int q = 0; q < 4; ++q) {
        raw[0].mm[q] = 1u << (3 - q);
        raw[0].ss[q] = 1u << (3 - q);
        raw[0].gidx[q] = 0;
    }
    raw[0].nw = 0;

    bool used[NL * NQ] = {false};
    int np = 1, remaining = ng;
    while (remaining > 0 && np < MAXP) {
        unsigned pss[4], pmm[4];
        int pgi[4], nw = 0;
        GF2Basis gf;
        for (int g = 0; g < ng && nw < 4; ++g) {
            if (used[g]) continue;
            bool ok = true;
            for (int k = 0; k < nw && ok; ++k)
                if (par16(gs[g] & pmm[k]) || par16(pss[k] & gm[g])) ok = false;
            for (int h = 0; h < g && ok; ++h)
                if (!used[h] && (par16(gs[g] & gm[h]) || par16(gs[h] & gm[g]))) ok = false;
            if (!ok) continue;
            GF2Basis trial = gf;
            if (!trial.insert(gm[g])) continue;
            gf = trial;
            pss[nw] = gs[g]; pmm[nw] = gm[g]; pgi[nw] = g; ++nw;
            used[g] = true; --remaining;
        }
        unsigned mm[4], ss[4];
        for (int i = 0; i < nw; ++i) { mm[i] = pmm[i]; ss[i] = pss[i]; }
        for (int i = nw; i < 4; ++i) {
            unsigned cand = 0;
            for (int t = 0; t < NQ; ++t)
                if (gf.insert(1u << t)) { cand = 1u << t; break; }
            for (int jq = 0; jq < nw; ++jq)
                if (par16(cand & ss[jq])) cand ^= mm[jq];
            mm[i] = cand; ss[i] = 0;
        }
        for (int q = 0; q < 4; ++q) { raw[np].mm[q] = mm[q]; raw[np].ss[q] = ss[q]; }
        for (int q = 0; q < 4; ++q)
            raw[np].gidx[q] = (unsigned char)(q < nw ? ggi[pgi[q]] : 0);
        raw[np].nw = (unsigned char)nw;

        // extras sweep
        {
            int exCirc[NEX]; int nExtra = 0;
            for (int g = 0; g < ng; ++g) {
                if (used[g]) continue;
                int c = -1;
                for (int t2 = 3; t2 < 16; ++t2) {
                    if (__builtin_popcount((unsigned)t2) < 2) continue;
                    unsigned xr = 0;
                    for (int jq = 0; jq < 4; ++jq) if ((t2 >> jq) & 1) xr ^= mm[jq];
                    if (xr == gm[g]) { c = t2; break; }
                }
                if (c < 0) continue;
                int slot = c2s[c];
                if (slot < 0 || raw[np].exgate[slot] >= 0) continue;
                unsigned T = 0;
                for (int jq = 0; jq < 4; ++jq)
                    T |= (unsigned)(par16(mm[jq] & gs[g]) & 1) << jq;
                {
                    int sp = 0;
                    for (int jq = 0; jq < 4; ++jq) if ((c >> jq) & 1) sp ^= (T >> jq) & 1;
                    if (!sp) continue;
                }
                bool ok = true;
                for (int e2 = 0; e2 < nExtra && ok; ++e2) {
                    int h = exCirc[e2];
                    if (par16(gs[g] & gm[h]) || par16(gs[h] & gm[g])) ok = false;
                }
                for (int kk = 0; kk < nw && ok; ++kk) {
                    int h = pgi[kk];
                    if (h > g && (par16(gs[g] & gm[h]) || par16(gs[h] & gm[g]))) ok = false;
                }
                for (int h = 0; h < g && ok; ++h)
                    if (!used[h] && (par16(gs[g] & gm[h]) || par16(gs[h] & gm[g]))) ok = false;
                if (!ok) continue;
                raw[np].exgate[slot] = ggi[g];
                raw[np].exsel[slot] = gs[g];
                raw[np].exT[slot] = T;
                exCirc[nExtra++] = g;
                used[g] = true; --remaining;
            }
        }
        ++np;
    }
    return np;
}

// ---------------- old-path emit (round-10 semantics) ----------------
static void old_emit(const RawEntry* raw, int np, const unsigned* msIdx,
                     ParamsG& h_pg, unsigned seed) {
    unsigned rvA[MAXP][10];
    for (int p = 0; p < np; ++p) {
        GF2Basis gf;
        for (int q = 0; q < 4; ++q) gf.insert(raw[p].mm[q]);
        int nR = 0;
        for (int t = 0; t < NQ && nR < 10; ++t) {
            if (gf.insert(1u << t)) {
                unsigned v = 1u << t;
                for (int q = 0; q < 4; ++q)
                    if (par16(v & raw[p].ss[q])) v ^= raw[p].mm[q];
                rvA[p][nR++] = v;
            }
        }
    }
    unsigned Cm[NQ], Ci[NQ];
    bool found = false;
    for (int tries = 0; tries < 5000 && !found; ++tries) {
        for (int j = 0; j < NQ; ++j) Cm[j] = lcg_next(seed) & (NSTATE - 1);
        if (!gf_invert(Cm, Ci)) continue;
        found = true;
        for (int p = 0; p < np && found; ++p) {
            unsigned piv[4] = {0, 0, 0, 0}; int npv = 0;
            for (int i = 0; i < 10; ++i) {
                unsigned w2 = gf_apply(Cm, rvA[p][i]);
                for (int bb = 0; bb < 4; ++bb)
                    if (((w2 >> bb) & 1u) && piv[bb]) w2 ^= piv[bb];
                if ((w2 & 15u) && npv < 4) { piv[__builtin_ctz(w2 & 15u)] = w2; ++npv; }
            }
            if (npv < 4) found = false;
        }
    }
    if (!found) { for (int j = 0; j < NQ; ++j) Cm[j] = 1u << j; gf_invert(Cm, Ci); }

    memset(&h_pg, 0, sizeof(h_pg));
    for (int p = 0; p < np; ++p) {
        unsigned u[10];
        for (int i = 0; i < 10; ++i) u[i] = gf_apply(Cm, rvA[p][i]);
        unsigned piv[4] = {0, 0, 0, 0};
        int ord[10], npv = 0, rest[10], nrest = 0;
        for (int i = 0; i < 10; ++i) {
            unsigned w2 = u[i];
            for (int bb = 0; bb < 4; ++bb)
                if (((w2 >> bb) & 1u) && piv[bb]) w2 ^= piv[bb];
            if ((w2 & 15u) && npv < 4) { piv[__builtin_ctz(w2 & 15u)] = w2; ord[npv++] = i; }
            else rest[nrest++] = i;
        }
        int kk = 0;
        for (int i = 0; i < npv; ++i) h_pg.pass[p].R[kk++] = u[ord[i]];
        for (int i = 0; i < nrest; ++i) h_pg.pass[p].R[kk++] = u[rest[i]];
        for (int idx = 0; idx < 16; ++idx) {
            unsigned c = 0;
            for (int q = 0; q < 4; ++q) if ((idx >> q) & 1) c ^= raw[p].mm[q];
            h_pg.pass[p].cmb8[idx] = gf_apply(Cm, c) << 3;
        }
        for (int q = 0; q < 4; ++q) h_pg.pass[p].gidx[q] = raw[p].gidx[q];
        h_pg.pass[p].nw = raw[p].nw;
        unsigned epm = 0;
        for (int k = 0; k < NEX; ++k) {
            if (raw[p].exgate[k] < 0) continue;
            epm |= 1u << k;
            unsigned sga = 0;
            for (int i = 0; i < NQ; ++i)
                sga |= (unsigned)(par16(Ci[i] & raw[p].exsel[k]) & 1) << i;
            h_pg.pass[p].eg[k] = sga | ((unsigned)raw[p].exgate[k] << 16);
            unsigned T = raw[p].exT[k], pw = 0;
            for (int i = 0; i < 16; ++i)
                pw |= (unsigned)(__builtin_popcount(i & T) & 1) << i;
            h_pg.pass[p].parw[k] = pw;
        }
        h_pg.pass[p].epm = epm;
    }
    for (int w = 0; w < NQ; ++w) {
        unsigned msp = 0;
        for (int i = 0; i < NQ; ++i)
            msp |= (unsigned)(par16(Ci[i] & msIdx[w]) & 1) << i;
        h_pg.ms[w] = msp;
    }
    for (int w = 0; w < NQ; ++w) {
        unsigned fm = 0;
        for (int i = 0; i < 16; ++i)
            fm |= (unsigned)(par16((h_pg.pass[np - 1].cmb8[i] >> 3) & h_pg.ms[w]) & 1) << i;
        h_pg.fmask[w] = fm;
    }
    {
        unsigned tmask[NQ];
        for (int w = 0; w < NQ; ++w) {
            unsigned t = 0;
            for (int i = 0; i < NQ; ++i)
                t |= (unsigned)((Ci[i] >> (NQ - 1 - w)) & 1u) << i;
            tmask[w] = t;
        }
        for (int j = 0; j < 10; ++j) {
            unsigned iw = 0;
            for (int w = 0; w < NQ; ++w)
                iw |= (unsigned)(par16(h_pg.pass[0].R[j] & tmask[w]) & 1) << w;
            h_pg.initIW[j] = iw;
        }
    }
}

// ---------------- split-path emit; returns 0 ok / reason 1..3 ----------------
static int try_split(const RawEntry* raw, int np, const unsigned* msIdx,
                     ParamsS& SP, unsigned seed) {
    if (np != 6) return 1;
    for (int p = 1; p < 6; ++p) if (raw[p].nw != 4) return 1;
    memset(&SP, 0, sizeof(SP));

    unsigned phi[2];
    for (int c = 0; c < 2; ++c) {
        unsigned bas[12]; int nb = 0;
        for (int p = c * 3; p < c * 3 + 3; ++p)
            for (int q = 0; q < 4; ++q) bas[nb++] = raw[p].mm[q];
        phi[c] = gf_nullfunc(bas, nb);
        if (!phi[c]) return 2;
    }
    // slot map rows: 0..11 = mu, 12 = phi1 (g1), 13 = phi2 (j)
    unsigned rows2[NQ];
    {
        GF2Basis rb;
        if (!rb.insert(phi[1])) return 2;
        if (!rb.insert(phi[0])) return 2;
        int nmu = 0;
        for (int t = 0; t < NQ && nmu < 12; ++t)
            if (rb.insert(1u << t)) rows2[nmu++] = 1u << t;
        if (nmu != 12) return 2;
        rows2[12] = phi[0];
        rows2[13] = phi[1];
    }
    unsigned colsM[NQ], Ci2[NQ];
    rows_to_cols(rows2, colsM);
    if (!gf_invert(colsM, Ci2)) return 2;
    // Ci2[k] k<12 = Vmu_k, Ci2[12] = G, Ci2[13] = J  (amp = XOR over slot bits)

    for (int k = 0; k < 2; ++k) {
        unsigned ph = phi[k];
        int p0e = k * 3;
        int pivbit = __builtin_ctz(ph);
        unsigned kb[13]; int nkb = 0;
        for (int t = 0; t < NQ; ++t) {
            if (t == pivbit) continue;
            unsigned v = 1u << t;
            if ((ph >> t) & 1u) v ^= 1u << pivbit;
            kb[nkb++] = v;
        }
        unsigned RvAll[3][9], UgAll[3];
        for (int pe = 0; pe < 3; ++pe) {
            const RawEntry& re = raw[p0e + pe];
            for (int q = 0; q < 4; ++q) if (par16(ph & re.mm[q])) return 2;
            GF2Basis gfb;
            for (int q = 0; q < 4; ++q) if (!gfb.insert(re.mm[q])) return 2;
            int nR = 0;
            for (int i = 0; i < 13 && nR < 9; ++i) {
                unsigned v = kb[i];
                if (gfb.insert(v)) {
                    for (int q = 0; q < 4; ++q)
                        if (par16(v & re.ss[q])) v ^= re.mm[q];
                    RvAll[pe][nR++] = v;
                }
            }
            if (nR != 9) return 2;
            unsigned ug = 1u << pivbit;
            for (int q = 0; q < 4; ++q)
                if (par16(ug & re.ss[q])) ug ^= re.mm[q];
            UgAll[pe] = ug;
        }
        // T search: [T;phi] invertible + bank rank-4 per entry
        unsigned T[13], Vt[NQ], Wt = 0;
        bool found = false;
        for (int tries = 0; tries < 20000 && !found; ++tries) {
            for (int i = 0; i < 13; ++i) T[i] = lcg_next(seed) & (NSTATE - 1);
            unsigned mrows[NQ], cm[NQ], ci[NQ];
            for (int i = 0; i < 13; ++i) mrows[i] = T[i];
            mrows[13] = ph;
            rows_to_cols(mrows, cm);
            if (!gf_invert(cm, ci)) continue;
            bool ok = true;
            for (int pe = 0; pe < 3 && ok; ++pe) {
                unsigned piv[4] = {0, 0, 0, 0}; int npv = 0;
                for (int i = 0; i < 9; ++i) {
                    unsigned w2 = addr_img(T, RvAll[pe][i]);
                    for (int bb = 0; bb < 4; ++bb)
                        if (((w2 >> bb) & 1u) && piv[bb]) w2 ^= piv[bb];
                    if ((w2 & 15u) && npv < 4) { piv[__builtin_ctz(w2 & 15u)] = w2; ++npv; }
                }
                if (npv < 4) ok = false;
            }
            if (!ok) continue;
            found = true;
            for (int i = 0; i < NQ; ++i) Vt[i] = ci[i];
            Wt = ci[13];
        }
        if (!found) return 3;

        PassK* PK = (k == 0) ? SP.k1.pass : SP.k2.pass;
        int ord0[9];  // entry-0 reorder (for initIW)
        for (int pe = 0; pe < 3; ++pe) {
            const RawEntry& re = raw[p0e + pe];
            PassK& P = PK[pe];
            unsigned img[9];
            for (int i = 0; i < 9; ++i) img[i] = addr_img(T, RvAll[pe][i]);
            unsigned piv[4] = {0, 0, 0, 0};
            int ord[9], npv = 0, rest[9], nrest = 0;
            for (int i = 0; i < 9; ++i) {
                unsigned w2 = img[i];
                for (int bb = 0; bb < 4; ++bb)
                    if (((w2 >> bb) & 1u) && piv[bb]) w2 ^= piv[bb];
                if ((w2 & 15u) && npv < 4) { piv[__builtin_ctz(w2 & 15u)] = w2; ord[npv++] = i; }
                else rest[nrest++] = i;
            }
            int kk = 0;
            for (int i = 0; i < npv; ++i)  { if (pe == 0) ord0[kk] = ord[i];  P.R[kk] = img[ord[i]];  ++kk; }
            for (int i = 0; i < nrest; ++i){ if (pe == 0) ord0[kk] = rest[i]; P.R[kk] = img[rest[i]]; ++kk; }
            P.Ug = addr_img(T, UgAll[pe]);
            for (int idx = 0; idx < 16; ++idx) {
                unsigned c = 0;
                for (int q = 0; q < 4; ++q) if ((idx >> q) & 1) c ^= re.mm[q];
                P.cmb8[idx] = addr_img(T, c) << 3;
            }
            for (int q = 0; q < 4; ++q) P.gidx[q] = re.gidx[q];
            P.nw = re.nw;
            unsigned epm = 0;
            for (int sl = 0; sl < NEX; ++sl) {
                if (re.exgate[sl] < 0) continue;
                epm |= 1u << sl;
                unsigned sga = 0;
                for (int i = 0; i < 13; ++i)
                    sga |= (unsigned)(par16(Vt[i] & re.exsel[sl]) & 1) << i;
                unsigned sgc = (unsigned)(par16(Wt & re.exsel[sl]) & 1);
                P.eg[sl] = sga | (sgc << 13) | ((unsigned)re.exgate[sl] << 16);
                unsigned Tq = re.exT[sl], pw = 0;
                for (int i = 0; i < 16; ++i)
                    pw |= (unsigned)(__builtin_popcount(i & Tq) & 1) << i;
                P.parw[sl] = pw;
            }
            P.epm = epm;
        }
        if (k == 0) {
            for (int jj = 0; jj < 9; ++jj) {
                unsigned v = RvAll[0][ord0[jj]], iw = 0;
                for (int w = 0; w < NQ; ++w)
                    iw |= ((v >> (NQ - 1 - w)) & 1u) << w;
                SP.k1.initIW[jj] = iw;
            }
            {
                unsigned v = UgAll[0], iw = 0;
                for (int w = 0; w < NQ; ++w)
                    iw |= ((v >> (NQ - 1 - w)) & 1u) << w;
                SP.k1.initIWg = iw;
            }
            for (int i = 0; i < 12; ++i) SP.k1.SK[i] = addr_img(T, Ci2[i]) << 3;
            SP.k1.SKg = addr_img(T, Ci2[12]) << 3;
            SP.k1.SKj = addr_img(T, Ci2[13]) << 3;
        } else {
            for (int i = 0; i < 12; ++i) SP.k2.SL[i] = addr_img(T, Ci2[i]) << 3;
            SP.k2.SL[12] = addr_img(T, Ci2[12]) << 3;
            SP.k2.SLj    = addr_img(T, Ci2[13]) << 3;
            for (int w = 0; w < NQ; ++w) {
                unsigned m13 = 0;
                for (int i = 0; i < 13; ++i)
                    m13 |= (unsigned)(par16(Vt[i] & msIdx[w]) & 1) << i;
                unsigned mg = (unsigned)(par16(Wt & msIdx[w]) & 1);
                SP.k2.ms[w] = m13 | (mg << 13);
            }
            for (int w = 0; w < NQ; ++w) {
                unsigned fm = 0;
                for (int i = 0; i < 16; ++i) {
                    unsigned c = 0;
                    for (int q = 0; q < 4; ++q) if ((i >> q) & 1) c ^= raw[5].mm[q];
                    fm |= (unsigned)(par16(c & msIdx[w]) & 1) << i;
                }
                SP.k2.fmask[w] = fm;
            }
        }
    }
    return 0;
}

// ---------------- launch ----------------
extern "C" void kernel_launch(void* const* d_in, const int* in_sizes, int n_in,
                              void* d_out, int out_size, void* d_ws, size_t ws_size,
                              hipStream_t stream) {
    const float* x  = (const float*)d_in[0];
    const float* qw = (const float*)d_in[1];
    const float* wl = (const float*)d_in[2];
    const float* bl = (const float*)d_in[3];
    float* out = (float*)d_out;

    const int B = in_sizes[0] / NQ;

    static RawEntry raw[MAXP];
    unsigned msIdx[NQ];
    int np = build_and_pack(raw, msIdx);

    static ParamsS h_sp;
    static ParamsG h_pg;
    const size_t parmoff = (size_t)B * NSTATE * 4;   // bf16-pair state = 8 MB
    const size_t need = parmoff + sizeof(ParamsS);

    int reason = try_split(raw, np, msIdx, h_sp, 0xC0FFEE13u);
    if (reason == 0 && ws_size < need) reason = 4;

    if (reason == 0) {
        hipMemcpyAsync((char*)d_ws + parmoff, &h_sp, sizeof(ParamsS),
                       hipMemcpyHostToDevice, stream);
        unsigned* stb = (unsigned*)d_ws;
        const ParamsS* pp = (const ParamsS*)((char*)d_ws + parmoff);
        qsim_k1<<<dim3(2 * B), dim3(BTS), 0, stream>>>(x, qw, pp, stb, out);
        qsim_k2<<<dim3(2 * B), dim3(BTS), 0, stream>>>(x, qw, wl, bl, pp, stb, out);
    } else {
        old_emit(raw, np, msIdx, h_pg, 0x9E3779B9u);
        hipMemcpyAsync(d_ws, &h_pg, sizeof(ParamsG), hipMemcpyHostToDevice, stream);
        const ParamsG* pg = (const ParamsG*)d_ws;
        switch (reason) {
            case 1:  qsim_fb<1><<<dim3(B), dim3(BT), 0, stream>>>(x, qw, wl, bl, out, pg, np); break;
            case 2:  qsim_fb<2><<<dim3(B), dim3(BT), 0, stream>>>(x, qw, wl, bl, out, pg, np); break;
            case 3:  qsim_fb<3><<<dim3(B), dim3(BT), 0, stream>>>(x, qw, wl, bl, out, pg, np); break;
            default: qsim_fb<4><<<dim3(B), dim3(BT), 0, stream>>>(x, qw, wl, bl, out, pg, np); break;
        }
    }
}